// Round 1
// baseline (910.688 us; speedup 1.0000x reference)
//
#include <hip/hip_runtime.h>
#include <cstdint>

// ---- problem constants ----
#define H_    2048
#define NQ_   16
#define NKV_  4
#define HD_   128
#define FF_   8192
#define B_    2
#define S_    2048
#define TOK   (B_*S_)            // 4096 tokens
#define QKVN  (H_ + 2*NKV_*HD_)  // 3072 = Q(2048) | K(512) | V(512)

typedef __bf16 bf16;
typedef bf16  bf16x8 __attribute__((ext_vector_type(8)));
typedef float f32x4  __attribute__((ext_vector_type(4)));

typedef __attribute__((address_space(1))) void as1_void;
typedef __attribute__((address_space(3))) void as3_void;

// async global->LDS, 16B per lane; LDS dest is wave-uniform base + lane*16
__device__ __forceinline__ void gload_lds16(const void* g, void* l) {
    __builtin_amdgcn_global_load_lds((as1_void*)g, (as3_void*)l, 16, 0, 0);
}

// ======================================================================
// Weight convert + transpose: W[K][N] f32 -> Wt[outOff+N][K] bf16
// ======================================================================
__global__ __launch_bounds__(256) void wtrans_kernel(
    const float* __restrict__ W, bf16* __restrict__ Wt, int K, int N, int outOff)
{
    __shared__ float tile[32][33];
    const int n0 = (int)blockIdx.x * 32;
    const int k0 = (int)blockIdx.y * 32;
    const int c  = (int)threadIdx.x & 31;
    const int r  = (int)threadIdx.x >> 5;   // 0..7
#pragma unroll
    for (int i = 0; i < 4; ++i)
        tile[r + i*8][c] = W[(size_t)(k0 + r + i*8) * N + n0 + c];
    __syncthreads();
#pragma unroll
    for (int i = 0; i < 4; ++i)
        Wt[(size_t)(outOff + n0 + r + i*8) * K + k0 + c] = (bf16)tile[c][r + i*8];
}

// pack bq|bk|bv -> [3072] f32
__global__ void biaspack_kernel(const float* __restrict__ bq, const float* __restrict__ bk,
                                const float* __restrict__ bv, float* __restrict__ out)
{
    const int i = (int)(blockIdx.x * 256 + threadIdx.x);
    out[i] = (i < H_) ? bq[i] : (i < H_ + NKV_*HD_ ? bk[i - H_] : bv[i - H_ - NKV_*HD_]);
}

// ======================================================================
// RMSNorm: x f32 [rows][2048] -> y bf16, y = g * x / sqrt(mean(x^2)+eps)
// ======================================================================
__global__ __launch_bounds__(256) void rmsnorm_kernel(
    const float* __restrict__ x, const float* __restrict__ g, bf16* __restrict__ y)
{
    const int row = (int)blockIdx.x;
    const int tid = (int)threadIdx.x;
    const float* xr = x + (size_t)row * H_;
    const float4 a = *(const float4*)(xr + tid*8);
    const float4 c = *(const float4*)(xr + tid*8 + 4);
    float ss = a.x*a.x + a.y*a.y + a.z*a.z + a.w*a.w
             + c.x*c.x + c.y*c.y + c.z*c.z + c.w*c.w;
#pragma unroll
    for (int d = 1; d < 64; d <<= 1) ss += __shfl_xor(ss, d);
    __shared__ float red[4];
    if ((tid & 63) == 0) red[tid >> 6] = ss;
    __syncthreads();
    const float inv = rsqrtf((red[0]+red[1]+red[2]+red[3]) * (1.0f/H_) + 1e-6f);
    const float vals[8] = {a.x,a.y,a.z,a.w,c.x,c.y,c.z,c.w};
    const float* gp = g + tid*8;
    bf16x8 outv;
#pragma unroll
    for (int e = 0; e < 8; ++e) outv[e] = (bf16)(vals[e] * inv * gp[e]);
    *(bf16x8*)(y + (size_t)row * H_ + tid*8) = outv;
}

// ======================================================================
// GEMM: C[M][N] = A[M][K] @ Bt[N][K]^T + bias, bf16 in, fp32 acc.
// 128x128 tile, BK=64, 4 waves each 64x64 (4x4 frags of 16x16x32 MFMA).
// LDS XOR-swizzle (elem ^= (row&7)*8) applied via pre-swizzled global src
// (global_load_lds writes linearly) + same XOR on the ds_read side.
// MODE 0: store bf16. MODE 1: exact GELU -> bf16. MODE 2: +resid -> f32.
// ======================================================================
template<int MODE>
__global__ __launch_bounds__(256) void gemm_kernel(
    const bf16* __restrict__ A, const bf16* __restrict__ Bt,
    const float* __restrict__ bias, const float* __restrict__ resid,
    void* __restrict__ Cout, int M, int N, int K)
{
    __shared__ bf16 lA[128*64];
    __shared__ bf16 lB[128*64];
    const int tid  = (int)threadIdx.x;
    const int wid  = tid >> 6;
    const int lane = tid & 63;
    const int lr   = lane & 15;
    const int lg   = lane >> 4;
    const int m0 = (int)blockIdx.y * 128;
    const int n0 = (int)blockIdx.x * 128;
    const int wm = (wid >> 1) * 64;
    const int wn = (wid & 1) * 64;

    f32x4 acc[4][4] = {};

    // staging: wave w covers rows [w*32, w*32+32); instr i -> 8 rows (1KB).
    // lane l fills LDS row (l>>3) of the chunk, col-bytes (l&7)*16.
    // source col pre-XOR'd so LDS[r][e] = src[r][e ^ (r&7)*8].
    const int sRow = wid*32 + (lane >> 3);
    const int sCol = ((lane & 7) ^ (lane >> 3)) * 8;
    const bf16* aSrc = A  + (size_t)(m0 + sRow) * K + sCol;
    const bf16* bSrc = Bt + (size_t)(n0 + sRow) * K + sCol;

    for (int k0 = 0; k0 < K; k0 += 64) {
#pragma unroll
        for (int i = 0; i < 4; ++i) {
            gload_lds16(aSrc + (size_t)(i*8)*K + k0, &lA[(wid*32 + i*8)*64]);
            gload_lds16(bSrc + (size_t)(i*8)*K + k0, &lB[(wid*32 + i*8)*64]);
        }
        __syncthreads();
#pragma unroll
        for (int kk = 0; kk < 64; kk += 32) {
            const int ks = (kk + lg*8) ^ ((lr & 7) * 8);  // swizzled k-offset
            bf16x8 af[4], bfr[4];
#pragma unroll
            for (int i = 0; i < 4; ++i)
                af[i] = *(const bf16x8*)&lA[(wm + i*16 + lr)*64 + ks];
#pragma unroll
            for (int j = 0; j < 4; ++j)
                bfr[j] = *(const bf16x8*)&lB[(wn + j*16 + lr)*64 + ks];
#pragma unroll
            for (int i = 0; i < 4; ++i)
#pragma unroll
                for (int j = 0; j < 4; ++j)
                    acc[i][j] = __builtin_amdgcn_mfma_f32_16x16x32_bf16(
                        af[i], bfr[j], acc[i][j], 0, 0, 0);
        }
        __syncthreads();
    }

    // epilogue: C row = m0+wm+i*16+lg*4+rr, col = n0+wn+j*16+lr
#pragma unroll
    for (int j = 0; j < 4; ++j) {
        const int col = n0 + wn + j*16 + lr;
        const float bj = bias[col];
#pragma unroll
        for (int i = 0; i < 4; ++i) {
            const int row0 = m0 + wm + i*16 + lg*4;
#pragma unroll
            for (int rr = 0; rr < 4; ++rr) {
                float v = acc[i][j][rr] + bj;
                const size_t idx = (size_t)(row0 + rr) * N + col;
                if (MODE == 2) {
                    ((float*)Cout)[idx] = v + resid[idx];
                } else {
                    if (MODE == 1) v = 0.5f * v * (1.0f + erff(v * 0.70710678118654752f));
                    ((bf16*)Cout)[idx] = (bf16)v;
                }
            }
        }
    }
}

// ======================================================================
// Flash attention (causal, GQA rep=4). Grid (S/64, NQ, B), 256 threads.
// Wave w owns q rows [qb+w*16, qb+w*16+16). KV tiles of 32.
// K tile: LDS [32][128] XOR-swizzled, staged via global_load_lds.
// V tile: LDS transposed [128][40] (pad 40 kills bank conflicts).
// Scores S[q][kv]: row=(lg*4+rr) matches ctx acc layout -> shuffle-free
// rescale. P goes through per-wave LDS to become the PV A-fragment.
// ======================================================================
__global__ __launch_bounds__(256) void attn_kernel(
    const bf16* __restrict__ qkv, bf16* __restrict__ ctx)
{
    __shared__ bf16 lK[32*128];
    __shared__ bf16 lV[128*40];
    __shared__ bf16 lP[4][16*40];
    const int tid  = (int)threadIdx.x;
    const int wid  = tid >> 6;
    const int lane = tid & 63;
    const int lr   = lane & 15;
    const int lg   = lane >> 4;
    const int qt = (int)blockIdx.x, h = (int)blockIdx.y, b = (int)blockIdx.z;
    const int kh = h >> 2;                 // REP = 4
    const int qb = qt * 64;
    const int qw = qb + wid * 16;
    const float scale = 0.08838834764831845f;  // 1/sqrt(128)

    // Q fragments in registers (row = lr, d = t*32 + lg*8 + i)
    bf16x8 qf[4];
    {
        const bf16* qp = qkv + (size_t)(b*S_ + qw + lr) * QKVN + h*HD_ + lg*8;
#pragma unroll
        for (int t = 0; t < 4; ++t) qf[t] = *(const bf16x8*)(qp + t*32);
    }
    f32x4 o[8] = {};
    float mrow[4] = {-__builtin_inff(), -__builtin_inff(), -__builtin_inff(), -__builtin_inff()};
    float lrow[4] = {0.f, 0.f, 0.f, 0.f};

    for (int kv0 = 0; kv0 < qb + 64; kv0 += 32) {
        __syncthreads();  // previous tile fully consumed
        // --- stage K[32][128] swizzled: chunk c = 4 rows; src col pre-XOR'd
#pragma unroll
        for (int i = 0; i < 2; ++i) {
            const int c   = wid*2 + i;
            const int row = c*4 + lg;
            const int ce  = (lr ^ (row & 7)) * 8;
            gload_lds16(qkv + (size_t)(b*S_ + kv0 + row) * QKVN + H_ + kh*HD_ + ce,
                        &lK[c*4*128]);
        }
        // --- stage V^T[128][40]: thread t loads 16 elems of row r, scatters
        {
            const int r  = tid >> 3;          // kv row 0..31
            const int e0 = (tid & 7) * 16;    // d
            const bf16* vp = qkv + (size_t)(b*S_ + kv0 + r) * QKVN + H_ + NKV_*HD_ + kh*HD_ + e0;
            const bf16x8 v0 = *(const bf16x8*)vp;
            const bf16x8 v1 = *(const bf16x8*)(vp + 8);
#pragma unroll
            for (int e = 0; e < 8; ++e) {
                lV[(e0 + e)*40 + r]     = v0[e];
                lV[(e0 + 8 + e)*40 + r] = v1[e];
            }
        }
        __syncthreads();

        // --- QK^T: S[q][kv], two 16-col sub-tiles
        f32x4 s[2] = {};
#pragma unroll
        for (int sub = 0; sub < 2; ++sub) {
            const int krow = sub*16 + lr;
#pragma unroll
            for (int t = 0; t < 4; ++t) {
                const int ks = (t*32 + lg*8) ^ ((krow & 7) * 8);
                const bf16x8 kf = *(const bf16x8*)&lK[krow*128 + ks];
                s[sub] = __builtin_amdgcn_mfma_f32_16x16x32_bf16(qf[t], kf, s[sub], 0, 0, 0);
            }
        }
        // --- scale + causal mask + row max
        float p[2][4], rmax[4];
#pragma unroll
        for (int rr = 0; rr < 4; ++rr) {
            const int q = qw + lg*4 + rr;
#pragma unroll
            for (int sub = 0; sub < 2; ++sub) {
                const int kv = kv0 + sub*16 + lr;
                const float v = s[sub][rr] * scale;
                p[sub][rr] = (kv <= q) ? v : -__builtin_inff();
            }
            rmax[rr] = fmaxf(p[0][rr], p[1][rr]);
        }
#pragma unroll
        for (int d = 1; d < 16; d <<= 1)
#pragma unroll
            for (int rr = 0; rr < 4; ++rr)
                rmax[rr] = fmaxf(rmax[rr], __shfl_xor(rmax[rr], d));
        // --- online softmax update
        float fsc[4], rsum[4];
#pragma unroll
        for (int rr = 0; rr < 4; ++rr) {
            const float mn = fmaxf(mrow[rr], rmax[rr]);
            fsc[rr]  = __expf(mrow[rr] - mn);   // 0 on first tile (mrow=-inf)
            mrow[rr] = mn;
            p[0][rr] = __expf(p[0][rr] - mn);
            p[1][rr] = __expf(p[1][rr] - mn);
            rsum[rr] = p[0][rr] + p[1][rr];
        }
#pragma unroll
        for (int d = 1; d < 16; d <<= 1)
#pragma unroll
            for (int rr = 0; rr < 4; ++rr)
                rsum[rr] += __shfl_xor(rsum[rr], d);
#pragma unroll
        for (int rr = 0; rr < 4; ++rr) lrow[rr] = lrow[rr]*fsc[rr] + rsum[rr];
#pragma unroll
        for (int t = 0; t < 8; ++t)
#pragma unroll
            for (int rr = 0; rr < 4; ++rr) o[t][rr] *= fsc[rr];
        // --- P -> LDS (per-wave), then PV
#pragma unroll
        for (int sub = 0; sub < 2; ++sub)
#pragma unroll
            for (int rr = 0; rr < 4; ++rr)
                lP[wid][(lg*4 + rr)*40 + sub*16 + lr] = (bf16)p[sub][rr];
        const bf16x8 pf = *(const bf16x8*)&lP[wid][lr*40 + lg*8];
#pragma unroll
        for (int t = 0; t < 8; ++t) {
            const bf16x8 vf = *(const bf16x8*)&lV[(t*16 + lr)*40 + lg*8];
            o[t] = __builtin_amdgcn_mfma_f32_16x16x32_bf16(pf, vf, o[t], 0, 0, 0);
        }
    }
    // --- normalize + store ctx[b, q, h*128 + d] bf16
#pragma unroll
    for (int rr = 0; rr < 4; ++rr) {
        const float inv = 1.0f / lrow[rr];
        bf16* cp = ctx + (size_t)(b*S_ + qw + lg*4 + rr) * H_ + h*HD_ + lr;
#pragma unroll
        for (int t = 0; t < 8; ++t)
            cp[t*16] = (bf16)(o[t][rr] * inv);
    }
}

// ======================================================================
extern "C" void kernel_launch(void* const* d_in, const int* in_sizes, int n_in,
                              void* d_out, int out_size, void* d_ws, size_t ws_size,
                              hipStream_t stream)
{
    const float* hidden = (const float*)d_in[0];
    const float* Wq = (const float*)d_in[1];
    const float* bq = (const float*)d_in[2];
    const float* Wk = (const float*)d_in[3];
    const float* bk = (const float*)d_in[4];
    const float* Wv = (const float*)d_in[5];
    const float* bv = (const float*)d_in[6];
    const float* Wo = (const float*)d_in[7];
    const float* bo = (const float*)d_in[8];
    const float* W1 = (const float*)d_in[9];
    const float* b1 = (const float*)d_in[10];
    const float* W2 = (const float*)d_in[11];
    const float* b2 = (const float*)d_in[12];
    const float* g1 = (const float*)d_in[13];
    const float* g2 = (const float*)d_in[14];
    float* out = (float*)d_out;

    char* p = (char*)d_ws;
    auto alloc = [&](size_t bytes) { char* r = p; p += (bytes + 255) & ~(size_t)255; return r; };
    bf16*  wt_qkv = (bf16*)alloc((size_t)QKVN * H_ * 2);   // [3072][2048]
    bf16*  wo_t   = (bf16*)alloc((size_t)H_ * H_ * 2);     // [2048][2048]
    bf16*  w1_t   = (bf16*)alloc((size_t)FF_ * H_ * 2);    // [8192][2048]
    bf16*  w2_t   = (bf16*)alloc((size_t)H_ * FF_ * 2);    // [2048][8192]
    float* bqkv   = (float*)alloc((size_t)QKVN * 4);
    bf16*  xn1    = (bf16*)alloc((size_t)TOK * H_ * 2);
    bf16*  qkv    = (bf16*)alloc((size_t)TOK * QKVN * 2);
    bf16*  ctxb   = (bf16*)alloc((size_t)TOK * H_ * 2);
    float* x1     = (float*)alloc((size_t)TOK * H_ * 4);
    bf16*  xn2    = (bf16*)alloc((size_t)TOK * H_ * 2);
    bf16*  ffn    = (bf16*)alloc((size_t)TOK * FF_ * 2);

    const dim3 blk(256);
    biaspack_kernel<<<dim3(QKVN/256), blk, 0, stream>>>(bq, bk, bv, bqkv);
    wtrans_kernel<<<dim3(H_/32,  H_/32),  blk, 0, stream>>>(Wq, wt_qkv, H_, H_,  0);
    wtrans_kernel<<<dim3(512/32, H_/32),  blk, 0, stream>>>(Wk, wt_qkv, H_, 512, H_);
    wtrans_kernel<<<dim3(512/32, H_/32),  blk, 0, stream>>>(Wv, wt_qkv, H_, 512, H_ + 512);
    wtrans_kernel<<<dim3(H_/32,  H_/32),  blk, 0, stream>>>(Wo, wo_t,   H_, H_,  0);
    wtrans_kernel<<<dim3(FF_/32, H_/32),  blk, 0, stream>>>(W1, w1_t,   H_, FF_, 0);
    wtrans_kernel<<<dim3(H_/32,  FF_/32), blk, 0, stream>>>(W2, w2_t,   FF_, H_, 0);

    rmsnorm_kernel<<<dim3(TOK), blk, 0, stream>>>(hidden, g1, xn1);
    gemm_kernel<0><<<dim3(QKVN/128, TOK/128), blk, 0, stream>>>(
        xn1, wt_qkv, bqkv, nullptr, qkv, TOK, QKVN, H_);
    attn_kernel<<<dim3(S_/64, NQ_, B_), blk, 0, stream>>>(qkv, ctxb);
    gemm_kernel<2><<<dim3(H_/128, TOK/128), blk, 0, stream>>>(
        ctxb, wo_t, bo, hidden, x1, TOK, H_, H_);
    rmsnorm_kernel<<<dim3(TOK), blk, 0, stream>>>(x1, g2, xn2);
    gemm_kernel<1><<<dim3(FF_/128, TOK/128), blk, 0, stream>>>(
        xn2, w1_t, b1, nullptr, ffn, TOK, FF_, H_);
    gemm_kernel<2><<<dim3(H_/128, TOK/128), blk, 0, stream>>>(
        ffn, w2_t, b2, x1, out, TOK, H_, FF_);
}

// Round 3
// 758.129 us; speedup vs baseline: 1.2012x; 1.2012x over previous
//
#include <hip/hip_runtime.h>
#include <cstdint>

// ---- problem constants ----
#define H_    2048
#define NQ_   16
#define NKV_  4
#define HD_   128
#define FF_   8192
#define B_    2
#define S_    2048
#define TOK   (B_*S_)            // 4096 tokens
#define QKVN  (H_ + 2*NKV_*HD_)  // 3072 = Q(2048) | K(512) | V(512)
#define KVB   64                 // attention KV tile

typedef __bf16 bf16;
typedef bf16  bf16x8 __attribute__((ext_vector_type(8)));
typedef float f32x4  __attribute__((ext_vector_type(4)));

typedef __attribute__((address_space(1))) void as1_void;
typedef __attribute__((address_space(3))) void as3_void;

// async global->LDS, 16B per lane; LDS dest is wave-uniform base + lane*16
__device__ __forceinline__ void gload_lds16(const void* g, void* l) {
    __builtin_amdgcn_global_load_lds((as1_void*)g, (as3_void*)l, 16, 0, 0);
}

// ======================================================================
// Weight convert + transpose: W[K][N] f32 -> Wt[outOff+N][K] bf16
// ======================================================================
__global__ __launch_bounds__(256) void wtrans_kernel(
    const float* __restrict__ W, bf16* __restrict__ Wt, int K, int N, int outOff)
{
    __shared__ float tile[32][33];
    const int n0 = (int)blockIdx.x * 32;
    const int k0 = (int)blockIdx.y * 32;
    const int c  = (int)threadIdx.x & 31;
    const int r  = (int)threadIdx.x >> 5;   // 0..7
#pragma unroll
    for (int i = 0; i < 4; ++i)
        tile[r + i*8][c] = W[(size_t)(k0 + r + i*8) * N + n0 + c];
    __syncthreads();
#pragma unroll
    for (int i = 0; i < 4; ++i)
        Wt[(size_t)(outOff + n0 + r + i*8) * K + k0 + c] = (bf16)tile[c][r + i*8];
}

// pack bq|bk|bv -> [3072] f32
__global__ void biaspack_kernel(const float* __restrict__ bq, const float* __restrict__ bk,
                                const float* __restrict__ bv, float* __restrict__ out)
{
    const int i = (int)(blockIdx.x * 256 + threadIdx.x);
    out[i] = (i < H_) ? bq[i] : (i < H_ + NKV_*HD_ ? bk[i - H_] : bv[i - H_ - NKV_*HD_]);
}

// ======================================================================
// RMSNorm: x f32 [rows][2048] -> y bf16
// ======================================================================
__global__ __launch_bounds__(256) void rmsnorm_kernel(
    const float* __restrict__ x, const float* __restrict__ g, bf16* __restrict__ y)
{
    const int row = (int)blockIdx.x;
    const int tid = (int)threadIdx.x;
    const float* xr = x + (size_t)row * H_;
    const float4 a = *(const float4*)(xr + tid*8);
    const float4 c = *(const float4*)(xr + tid*8 + 4);
    float ss = a.x*a.x + a.y*a.y + a.z*a.z + a.w*a.w
             + c.x*c.x + c.y*c.y + c.z*c.z + c.w*c.w;
#pragma unroll
    for (int d = 1; d < 64; d <<= 1) ss += __shfl_xor(ss, d);
    __shared__ float red[4];
    if ((tid & 63) == 0) red[tid >> 6] = ss;
    __syncthreads();
    const float inv = rsqrtf((red[0]+red[1]+red[2]+red[3]) * (1.0f/H_) + 1e-6f);
    const float vals[8] = {a.x,a.y,a.z,a.w,c.x,c.y,c.z,c.w};
    const float* gp = g + tid*8;
    bf16x8 outv;
#pragma unroll
    for (int e = 0; e < 8; ++e) outv[e] = (bf16)(vals[e] * inv * gp[e]);
    *(bf16x8*)(y + (size_t)row * H_ + tid*8) = outv;
}

// ======================================================================
// V transpose: qkv[tok][3072] V-slice -> Vt[(b*NKV+kh)*HD + d][S]
// ======================================================================
__global__ __launch_bounds__(256) void vtrans_kernel(
    const bf16* __restrict__ qkv, bf16* __restrict__ Vt)
{
    __shared__ bf16 tile[32][33];
    const int tt = (int)blockIdx.x;          // token tile (32 tokens)
    const int d0 = (int)blockIdx.y * 32;
    const int kh = (int)blockIdx.z;
    const int b  = (tt*32) / S_;
    const int s0 = (tt*32) % S_;
    const int c = (int)threadIdx.x & 31;
    const int r = (int)threadIdx.x >> 5;     // 0..7
#pragma unroll
    for (int i = 0; i < 4; ++i)
        tile[r + i*8][c] = qkv[(size_t)(tt*32 + r + i*8)*QKVN + H_ + NKV_*HD_ + kh*HD_ + d0 + c];
    __syncthreads();
#pragma unroll
    for (int i = 0; i < 4; ++i)
        Vt[((size_t)(b*NKV_ + kh)*HD_ + d0 + r + i*8)*S_ + s0 + c] = tile[c][r + i*8];
}

// ======================================================================
// GEMM: C[M][N] = A[M][K] @ Bt[N][K]^T + bias
// ======================================================================
template<int MODE>
__global__ __launch_bounds__(256) void gemm_kernel(
    const bf16* __restrict__ A, const bf16* __restrict__ Bt,
    const float* __restrict__ bias, const float* __restrict__ resid,
    void* __restrict__ Cout, int M, int N, int K)
{
    __shared__ bf16 lA[128*64];
    __shared__ bf16 lB[128*64];
    const int tid  = (int)threadIdx.x;
    const int wid  = tid >> 6;
    const int lane = tid & 63;
    const int lr   = lane & 15;
    const int lg   = lane >> 4;
    const int m0 = (int)blockIdx.y * 128;
    const int n0 = (int)blockIdx.x * 128;
    const int wm = (wid >> 1) * 64;
    const int wn = (wid & 1) * 64;

    f32x4 acc[4][4] = {};

    const int sRow = wid*32 + (lane >> 3);
    const int sCol = ((lane & 7) ^ (lane >> 3)) * 8;
    const bf16* aSrc = A  + (size_t)(m0 + sRow) * K + sCol;
    const bf16* bSrc = Bt + (size_t)(n0 + sRow) * K + sCol;

    for (int k0 = 0; k0 < K; k0 += 64) {
#pragma unroll
        for (int i = 0; i < 4; ++i) {
            gload_lds16(aSrc + (size_t)(i*8)*K + k0, &lA[(wid*32 + i*8)*64]);
            gload_lds16(bSrc + (size_t)(i*8)*K + k0, &lB[(wid*32 + i*8)*64]);
        }
        __syncthreads();
#pragma unroll
        for (int kk = 0; kk < 64; kk += 32) {
            const int ks = (kk + lg*8) ^ ((lr & 7) * 8);
            bf16x8 af[4], bfr[4];
#pragma unroll
            for (int i = 0; i < 4; ++i)
                af[i] = *(const bf16x8*)&lA[(wm + i*16 + lr)*64 + ks];
#pragma unroll
            for (int j = 0; j < 4; ++j)
                bfr[j] = *(const bf16x8*)&lB[(wn + j*16 + lr)*64 + ks];
#pragma unroll
            for (int i = 0; i < 4; ++i)
#pragma unroll
                for (int j = 0; j < 4; ++j)
                    acc[i][j] = __builtin_amdgcn_mfma_f32_16x16x32_bf16(
                        af[i], bfr[j], acc[i][j], 0, 0, 0);
        }
        __syncthreads();
    }

#pragma unroll
    for (int j = 0; j < 4; ++j) {
        const int col = n0 + wn + j*16 + lr;
        const float bj = bias[col];
#pragma unroll
        for (int i = 0; i < 4; ++i) {
            const int row0 = m0 + wm + i*16 + lg*4;
#pragma unroll
            for (int rr = 0; rr < 4; ++rr) {
                float v = acc[i][j][rr] + bj;
                const size_t idx = (size_t)(row0 + rr) * N + col;
                if (MODE == 2) {
                    ((float*)Cout)[idx] = v + resid[idx];
                } else {
                    if (MODE == 1) v = 0.5f * v * (1.0f + erff(v * 0.70710678118654752f));
                    ((bf16*)Cout)[idx] = (bf16)v;
                }
            }
        }
    }
}

// ======================================================================
// Flash attention v2 (causal, GQA rep=4). Grid (S/64, NQ, B), 256 thr.
// KVB=64, double-buffered K/Vt staging via global_load_lds (swizzled
// source, linear LDS dest), one barrier per tile. Wave w: q rows
// [qb+16w, qb+16w+16). Mask only on the diagonal tile.
// ======================================================================
__global__ __launch_bounds__(256) void attn_kernel(
    const bf16* __restrict__ qkv, const bf16* __restrict__ Vt,
    bf16* __restrict__ ctx)
{
    __shared__ bf16 lK[2][KVB*HD_];   // [64][128], granule-XOR swizzled
    __shared__ bf16 lV[2][HD_*KVB];   // [128][64], granule-XOR swizzled
    __shared__ bf16 lP[4][16*72];     // per-wave P round-trip
    const int tid  = (int)threadIdx.x;
    const int wid  = tid >> 6;
    const int lane = tid & 63;
    const int lr   = lane & 15;
    const int lg   = lane >> 4;
    const int qt = (int)gridDim.x - 1 - (int)blockIdx.x;  // heavy tiles first
    const int h = (int)blockIdx.y, b = (int)blockIdx.z;
    const int kh = h >> 2;               // REP = 4
    const int qb = qt * 64;
    const int qw = qb + wid * 16;
    const float scale = 0.08838834764831845f;   // 1/sqrt(128)

    // ---- staging source pointers (pre-swizzled columns) ----
    const bf16* kB[4];
    const bf16* vB[4];
#pragma unroll
    for (int i = 0; i < 4; ++i) {
        const int kRow = (wid*4 + i)*4 + (lane >> 4);            // 0..63
        const int kCol = ((lane & 15) ^ (kRow & 7)) * 8;          // elems
        kB[i] = qkv + (size_t)(b*S_ + kRow)*QKVN + H_ + kh*HD_ + kCol;
        const int vRow = (wid*4 + i)*8 + (lane >> 3);            // d: 0..127
        const int vCol = ((lane & 7) ^ (vRow & 7)) * 8;           // elems
        vB[i] = Vt + ((size_t)(b*NKV_ + kh)*HD_ + vRow)*S_ + vCol;
    }

    // ---- Q fragments in registers: row=lr, k = t*32 + lg*8 + i ----
    bf16x8 qf[4];
    {
        const bf16* qp = qkv + (size_t)(b*S_ + qw + lr)*QKVN + h*HD_ + lg*8;
#pragma unroll
        for (int t = 0; t < 4; ++t) qf[t] = *(const bf16x8*)(qp + t*32);
    }

    f32x4 o[8] = {};
    float mrow[4] = {-__builtin_inff(), -__builtin_inff(), -__builtin_inff(), -__builtin_inff()};
    float lrow[4] = {0.f, 0.f, 0.f, 0.f};
    const int nt = qt + 1;

    // prologue: stage tile 0 into buffer 0
#pragma unroll
    for (int i = 0; i < 4; ++i) {
        gload_lds16(kB[i], &lK[0][(wid*4 + i)*4*HD_]);
        gload_lds16(vB[i], &lV[0][(wid*4 + i)*8*KVB]);
    }

    int cur = 0;
    for (int t = 0; t < nt; ++t) {
        __syncthreads();   // drains vmcnt -> buffer `cur` ready; `cur^1` free
        if (t + 1 < nt) {
            const size_t kAdd = (size_t)(t+1)*KVB*QKVN;   // +64 kv rows
            const size_t vAdd = (size_t)(t+1)*KVB;        // +64 kv cols
#pragma unroll
            for (int i = 0; i < 4; ++i) {
                gload_lds16(kB[i] + kAdd, &lK[cur^1][(wid*4 + i)*4*HD_]);
                gload_lds16(vB[i] + vAdd, &lV[cur^1][(wid*4 + i)*8*KVB]);
            }
        }
        const int kv0 = t * KVB;

        // ---- QK^T: S[q][kv], 4 sub-tiles of 16 kv ----
        f32x4 s[4] = {};
#pragma unroll
        for (int sub = 0; sub < 4; ++sub) {
            const int krow = sub*16 + lr;
            const bf16* kr = &lK[cur][krow*HD_];
            const int sw = (krow & 7) * 8;
#pragma unroll
            for (int d = 0; d < 4; ++d) {
                const bf16x8 kf = *(const bf16x8*)(kr + ((d*32 + lg*8) ^ sw));
                s[sub] = __builtin_amdgcn_mfma_f32_16x16x32_bf16(qf[d], kf, s[sub], 0, 0, 0);
            }
        }

        // ---- scale + (diagonal-only) causal mask + row max ----
        float p[4][4], rmax[4];
        if (t == qt) {
#pragma unroll
            for (int rr = 0; rr < 4; ++rr) {
                const int q = qw + lg*4 + rr;
                rmax[rr] = -__builtin_inff();
#pragma unroll
                for (int sub = 0; sub < 4; ++sub) {
                    const int kv = kv0 + sub*16 + lr;
                    const float v = s[sub][rr] * scale;
                    p[sub][rr] = (kv <= q) ? v : -__builtin_inff();
                    rmax[rr] = fmaxf(rmax[rr], p[sub][rr]);
                }
            }
        } else {
#pragma unroll
            for (int rr = 0; rr < 4; ++rr) {
                rmax[rr] = -__builtin_inff();
#pragma unroll
                for (int sub = 0; sub < 4; ++sub) {
                    p[sub][rr] = s[sub][rr] * scale;
                    rmax[rr] = fmaxf(rmax[rr], p[sub][rr]);
                }
            }
        }
#pragma unroll
        for (int d = 1; d < 16; d <<= 1)
#pragma unroll
            for (int rr = 0; rr < 4; ++rr)
                rmax[rr] = fmaxf(rmax[rr], __shfl_xor(rmax[rr], d));

        // ---- online softmax update ----
        float fsc[4], rsum[4];
#pragma unroll
        for (int rr = 0; rr < 4; ++rr) {
            const float mn = fmaxf(mrow[rr], rmax[rr]);
            fsc[rr]  = __expf(mrow[rr] - mn);
            mrow[rr] = mn;
            rsum[rr] = 0.f;
#pragma unroll
            for (int sub = 0; sub < 4; ++sub) {
                p[sub][rr] = __expf(p[sub][rr] - mn);
                rsum[rr] += p[sub][rr];
            }
        }
#pragma unroll
        for (int d = 1; d < 16; d <<= 1)
#pragma unroll
            for (int rr = 0; rr < 4; ++rr)
                rsum[rr] += __shfl_xor(rsum[rr], d);
#pragma unroll
        for (int rr = 0; rr < 4; ++rr) lrow[rr] = lrow[rr]*fsc[rr] + rsum[rr];
#pragma unroll
        for (int dch = 0; dch < 8; ++dch)
#pragma unroll
            for (int rr = 0; rr < 4; ++rr) o[dch][rr] *= fsc[rr];

        // ---- P -> per-wave LDS, read back as PV A-fragments ----
#pragma unroll
        for (int sub = 0; sub < 4; ++sub)
#pragma unroll
            for (int rr = 0; rr < 4; ++rr)
                lP[wid][(lg*4 + rr)*72 + sub*16 + lr] = (bf16)p[sub][rr];
        bf16x8 pf[2];
#pragma unroll
        for (int kk = 0; kk < 2; ++kk)
            pf[kk] = *(const bf16x8*)&lP[wid][lr*72 + kk*32 + lg*8];

        // ---- PV: o[q][d] += P[q][kv] * V[kv][d] ----
#pragma unroll
        for (int dch = 0; dch < 8; ++dch) {
            const bf16* vr = &lV[cur][(dch*16 + lr)*KVB];
            const int sw = (lr & 7) * 8;
#pragma unroll
            for (int kk = 0; kk < 2; ++kk) {
                const bf16x8 vf = *(const bf16x8*)(vr + ((kk*32 + lg*8) ^ sw));
                o[dch] = __builtin_amdgcn_mfma_f32_16x16x32_bf16(pf[kk], vf, o[dch], 0, 0, 0);
            }
        }
        cur ^= 1;
    }

    // ---- normalize + store ctx[b, q, h*128 + d] bf16 ----
#pragma unroll
    for (int rr = 0; rr < 4; ++rr) {
        const float inv = 1.0f / lrow[rr];
        bf16* cp = ctx + (size_t)(b*S_ + qw + lg*4 + rr) * H_ + h*HD_ + lr;
#pragma unroll
        for (int dch = 0; dch < 8; ++dch)
            cp[dch*16] = (bf16)(o[dch][rr] * inv);
    }
}

// ======================================================================
extern "C" void kernel_launch(void* const* d_in, const int* in_sizes, int n_in,
                              void* d_out, int out_size, void* d_ws, size_t ws_size,
                              hipStream_t stream)
{
    const float* hidden = (const float*)d_in[0];
    const float* Wq = (const float*)d_in[1];
    const float* bq = (const float*)d_in[2];
    const float* Wk = (const float*)d_in[3];
    const float* bk = (const float*)d_in[4];
    const float* Wv = (const float*)d_in[5];
    const float* bv = (const float*)d_in[6];
    const float* Wo = (const float*)d_in[7];
    const float* bo = (const float*)d_in[8];
    const float* W1 = (const float*)d_in[9];
    const float* b1 = (const float*)d_in[10];
    const float* W2 = (const float*)d_in[11];
    const float* b2 = (const float*)d_in[12];
    const float* g1 = (const float*)d_in[13];
    const float* g2 = (const float*)d_in[14];
    float* out = (float*)d_out;

    // Workspace budget: d_ws is 256 MiB; round-2 overflowed it by 12 KB by
    // appending vt (4 MB). Fix: vt ALIASES xn1's region (xn1 is dead after
    // the QKV GEMM; vt is written after and dead before xn1's region is
    // touched again). Total footprint = 264,253,440 B (= round-1, proven).
    char* p = (char*)d_ws;
    auto alloc = [&](size_t bytes) { char* r = p; p += (bytes + 255) & ~(size_t)255; return r; };
    bf16*  wt_qkv = (bf16*)alloc((size_t)QKVN * H_ * 2);   // [3072][2048]
    bf16*  wo_t   = (bf16*)alloc((size_t)H_ * H_ * 2);
    bf16*  w1_t   = (bf16*)alloc((size_t)FF_ * H_ * 2);
    bf16*  w2_t   = (bf16*)alloc((size_t)H_ * FF_ * 2);
    float* bqkv   = (float*)alloc((size_t)QKVN * 4);
    bf16*  xn1    = (bf16*)alloc((size_t)TOK * H_ * 2);    // 16 MB
    bf16*  qkv    = (bf16*)alloc((size_t)TOK * QKVN * 2);
    bf16*  ctxb   = (bf16*)alloc((size_t)TOK * H_ * 2);
    float* x1     = (float*)alloc((size_t)TOK * H_ * 4);
    bf16*  xn2    = (bf16*)alloc((size_t)TOK * H_ * 2);
    bf16*  ffn    = (bf16*)alloc((size_t)TOK * FF_ * 2);
    bf16*  vt     = xn1;   // alias: 4 MB Vt lives in dead xn1 region

    const dim3 blk(256);
    biaspack_kernel<<<dim3(QKVN/256), blk, 0, stream>>>(bq, bk, bv, bqkv);
    wtrans_kernel<<<dim3(H_/32,  H_/32),  blk, 0, stream>>>(Wq, wt_qkv, H_, H_,  0);
    wtrans_kernel<<<dim3(512/32, H_/32),  blk, 0, stream>>>(Wk, wt_qkv, H_, 512, H_);
    wtrans_kernel<<<dim3(512/32, H_/32),  blk, 0, stream>>>(Wv, wt_qkv, H_, 512, H_ + 512);
    wtrans_kernel<<<dim3(H_/32,  H_/32),  blk, 0, stream>>>(Wo, wo_t,   H_, H_,  0);
    wtrans_kernel<<<dim3(FF_/32, H_/32),  blk, 0, stream>>>(W1, w1_t,   H_, FF_, 0);
    wtrans_kernel<<<dim3(H_/32,  FF_/32), blk, 0, stream>>>(W2, w2_t,   FF_, H_, 0);

    rmsnorm_kernel<<<dim3(TOK), blk, 0, stream>>>(hidden, g1, xn1);
    gemm_kernel<0><<<dim3(QKVN/128, TOK/128), blk, 0, stream>>>(
        xn1, wt_qkv, bqkv, nullptr, qkv, TOK, QKVN, H_);
    vtrans_kernel<<<dim3(TOK/32, HD_/32, NKV_), blk, 0, stream>>>(qkv, vt);
    attn_kernel<<<dim3(S_/64, NQ_, B_), blk, 0, stream>>>(qkv, vt, ctxb);
    gemm_kernel<2><<<dim3(H_/128, TOK/128), blk, 0, stream>>>(
        ctxb, wo_t, bo, hidden, x1, TOK, H_, H_);
    rmsnorm_kernel<<<dim3(TOK), blk, 0, stream>>>(x1, g2, xn2);
    gemm_kernel<1><<<dim3(FF_/128, TOK/128), blk, 0, stream>>>(
        xn2, w1_t, b1, nullptr, ffn, TOK, FF_, H_);
    gemm_kernel<2><<<dim3(H_/128, TOK/128), blk, 0, stream>>>(
        ffn, w2_t, b2, x1, out, TOK, H_, FF_);
}

// Round 4
// 753.051 us; speedup vs baseline: 1.2093x; 1.0067x over previous
//
#include <hip/hip_runtime.h>
#include <cstdint>

// ---- problem constants ----
#define H_    2048
#define NQ_   16
#define NKV_  4
#define HD_   128
#define FF_   8192
#define B_    2
#define S_    2048
#define TOK   (B_*S_)            // 4096 tokens
#define QKVN  (H_ + 2*NKV_*HD_)  // 3072 = Q(2048) | K(512) | V(512)
#define KVB   64                 // attention KV tile

// GEMM2 geometry
#define BM 256
#define BN 128
#define BKG 64

typedef __bf16 bf16;
typedef bf16  bf16x8 __attribute__((ext_vector_type(8)));
typedef float f32x4  __attribute__((ext_vector_type(4)));

typedef __attribute__((address_space(1))) void as1_void;
typedef __attribute__((address_space(3))) void as3_void;

// async global->LDS, 16B per lane; LDS dest is wave-uniform base + lane*16
__device__ __forceinline__ void gload_lds16(const void* g, void* l) {
    __builtin_amdgcn_global_load_lds((as1_void*)g, (as3_void*)l, 16, 0, 0);
}

// ======================================================================
// Weight convert + transpose: W[K][N] f32 -> Wt[outOff+N][K] bf16
// ======================================================================
__global__ __launch_bounds__(256) void wtrans_kernel(
    const float* __restrict__ W, bf16* __restrict__ Wt, int K, int N, int outOff)
{
    __shared__ float tile[32][33];
    const int n0 = (int)blockIdx.x * 32;
    const int k0 = (int)blockIdx.y * 32;
    const int c  = (int)threadIdx.x & 31;
    const int r  = (int)threadIdx.x >> 5;   // 0..7
#pragma unroll
    for (int i = 0; i < 4; ++i)
        tile[r + i*8][c] = W[(size_t)(k0 + r + i*8) * N + n0 + c];
    __syncthreads();
#pragma unroll
    for (int i = 0; i < 4; ++i)
        Wt[(size_t)(outOff + n0 + r + i*8) * K + k0 + c] = (bf16)tile[c][r + i*8];
}

// pack bq|bk|bv -> [3072] f32
__global__ void biaspack_kernel(const float* __restrict__ bq, const float* __restrict__ bk,
                                const float* __restrict__ bv, float* __restrict__ out)
{
    const int i = (int)(blockIdx.x * 256 + threadIdx.x);
    out[i] = (i < H_) ? bq[i] : (i < H_ + NKV_*HD_ ? bk[i - H_] : bv[i - H_ - NKV_*HD_]);
}

// ======================================================================
// RMSNorm: x f32 [rows][2048] -> y bf16
// ======================================================================
__global__ __launch_bounds__(256) void rmsnorm_kernel(
    const float* __restrict__ x, const float* __restrict__ g, bf16* __restrict__ y)
{
    const int row = (int)blockIdx.x;
    const int tid = (int)threadIdx.x;
    const float* xr = x + (size_t)row * H_;
    const float4 a = *(const float4*)(xr + tid*8);
    const float4 c = *(const float4*)(xr + tid*8 + 4);
    float ss = a.x*a.x + a.y*a.y + a.z*a.z + a.w*a.w
             + c.x*c.x + c.y*c.y + c.z*c.z + c.w*c.w;
#pragma unroll
    for (int d = 1; d < 64; d <<= 1) ss += __shfl_xor(ss, d);
    __shared__ float red[4];
    if ((tid & 63) == 0) red[tid >> 6] = ss;
    __syncthreads();
    const float inv = rsqrtf((red[0]+red[1]+red[2]+red[3]) * (1.0f/H_) + 1e-6f);
    const float vals[8] = {a.x,a.y,a.z,a.w,c.x,c.y,c.z,c.w};
    const float* gp = g + tid*8;
    bf16x8 outv;
#pragma unroll
    for (int e = 0; e < 8; ++e) outv[e] = (bf16)(vals[e] * inv * gp[e]);
    *(bf16x8*)(y + (size_t)row * H_ + tid*8) = outv;
}

// ======================================================================
// V transpose: qkv[tok][3072] V-slice -> Vt[(b*NKV+kh)*HD + d][S]
// ======================================================================
__global__ __launch_bounds__(256) void vtrans_kernel(
    const bf16* __restrict__ qkv, bf16* __restrict__ Vt)
{
    __shared__ bf16 tile[32][33];
    const int tt = (int)blockIdx.x;          // token tile (32 tokens)
    const int d0 = (int)blockIdx.y * 32;
    const int kh = (int)blockIdx.z;
    const int b  = (tt*32) / S_;
    const int s0 = (tt*32) % S_;
    const int c = (int)threadIdx.x & 31;
    const int r = (int)threadIdx.x >> 5;     // 0..7
#pragma unroll
    for (int i = 0; i < 4; ++i)
        tile[r + i*8][c] = qkv[(size_t)(tt*32 + r + i*8)*QKVN + H_ + NKV_*HD_ + kh*HD_ + d0 + c];
    __syncthreads();
#pragma unroll
    for (int i = 0; i < 4; ++i)
        Vt[((size_t)(b*NKV_ + kh)*HD_ + d0 + r + i*8)*S_ + s0 + c] = tile[c][r + i*8];
}

// ======================================================================
// GEMM v2: C[M][N] = A[M][K] @ Bt[N][K]^T + bias, bf16 in, fp32 acc.
// 256x128 tile, BK=64, 8 waves (512 thr) each owning 64x64 (4x4 frags).
// THREE LDS buffers (A 96KB + B 48KB = 144KB): tile t+2 staged during
// tile t into the buffer tile t-1 vacated -> race-free counted-vmcnt
// pipeline; vmcnt(6) once per K-tile, never 0 in steady state. Raw
// s_barrier (no __syncthreads -> no vmcnt(0) drain). T2 st_16x32
// swizzle via pre-swizzled source; T5 setprio around MFMA clusters.
// MODE 0: bf16 out. MODE 1: exact GELU -> bf16. MODE 2: +resid -> f32.
// ======================================================================
template<int MODE>
__global__ __launch_bounds__(512, 1) void gemm2_kernel(
    const bf16* __restrict__ A, const bf16* __restrict__ Bt,
    const float* __restrict__ bias, const float* __restrict__ resid,
    void* __restrict__ Cout, int M, int N, int K)
{
    __shared__ bf16 lA[3][BM*BKG];   // 3 x 32KB
    __shared__ bf16 lB[3][BN*BKG];   // 3 x 16KB
    const int tid  = (int)threadIdx.x;
    const int wid  = tid >> 6;        // 0..7
    const int lane = tid & 63;
    const int lr   = lane & 15;
    const int lg   = lane >> 4;

    // ---- XCD-aware block swizzle (all grids have nwg % 8 == 0) ----
    const int gx  = (int)gridDim.x;
    const int nwg = gx * (int)gridDim.y;
    int wg = (int)blockIdx.y * gx + (int)blockIdx.x;
    if ((nwg & 7) == 0) wg = (wg & 7) * (nwg >> 3) + (wg >> 3);
    const int n0 = (wg % gx) * BN;
    const int m0 = (wg / gx) * BM;

    const int wr = wid >> 1;          // 0..3 -> M offset wr*64
    const int wc = wid & 1;           // 0..1 -> N offset wc*64

    // ---- staging: per gload instr, wave w covers 8 rows of a 64-row chunk.
    // row = chunk*64 + wid*8 + (lane>>3); src col pre-XOR'd for st_16x32:
    // LDS[r][c] = src[r][c ^ ((r>>3)&1)*16]; here (r>>3)&1 == wid&1.
    const int srow = wid*8 + (lane >> 3);
    const int scol = ((lane & 7) * 8) ^ ((wid & 1) * 16);
    const bf16* aS = A  + (size_t)(m0 + srow) * K + scol;
    const bf16* bS = Bt + (size_t)(n0 + srow) * K + scol;

    f32x4 acc[4][4] = {};
    const int nt = K / BKG;

    // ---- prologue: stage tiles 0 and 1 ----
#pragma unroll
    for (int i = 0; i < 4; ++i)
        gload_lds16(aS + (size_t)i*64*K, &lA[0][(i*64 + wid*8)*BKG]);
#pragma unroll
    for (int j = 0; j < 2; ++j)
        gload_lds16(bS + (size_t)j*64*K, &lB[0][(j*64 + wid*8)*BKG]);
#pragma unroll
    for (int i = 0; i < 4; ++i)
        gload_lds16(aS + (size_t)i*64*K + BKG, &lA[1][(i*64 + wid*8)*BKG]);
#pragma unroll
    for (int j = 0; j < 2; ++j)
        gload_lds16(bS + (size_t)j*64*K + BKG, &lB[1][(j*64 + wid*8)*BKG]);
    asm volatile("s_waitcnt vmcnt(6)" ::: "memory");  // tile 0 landed (6 = tile 1)
    __builtin_amdgcn_s_barrier();

    const int sw = ((lane >> 3) & 1) * 16;  // read-side swizzle XOR
    int cur = 0;
    for (int t = 0; t < nt; ++t) {
        const bf16* lAc = lA[cur];
        const bf16* lBc = lB[cur];
        const int   pc  = (cur + 2 >= 3) ? cur - 1 : cur + 2;  // (t+2)%3
        const size_t nk0 = (size_t)(t + 2) * BKG;
        const bool  pf  = (t + 2) < nt;

        // ================= phase 1: quadrant mf0-1 x nf0-3 =================
        bf16x8 af[2][2], bfr[4][2];
#pragma unroll
        for (int mf = 0; mf < 2; ++mf)
#pragma unroll
            for (int ks = 0; ks < 2; ++ks)
                af[mf][ks] = *(const bf16x8*)&lAc[(wr*64 + mf*16 + lr)*BKG + ((ks*32 + lg*8) ^ sw)];
#pragma unroll
        for (int nf = 0; nf < 4; ++nf)
#pragma unroll
            for (int ks = 0; ks < 2; ++ks)
                bfr[nf][ks] = *(const bf16x8*)&lBc[(wc*64 + nf*16 + lr)*BKG + ((ks*32 + lg*8) ^ sw)];
        if (pf) {
            gload_lds16(aS + (size_t)0*64*K + nk0, &lA[pc][(0*64 + wid*8)*BKG]);
            gload_lds16(aS + (size_t)1*64*K + nk0, &lA[pc][(1*64 + wid*8)*BKG]);
            gload_lds16(aS + (size_t)2*64*K + nk0, &lA[pc][(2*64 + wid*8)*BKG]);
        }
        __builtin_amdgcn_s_barrier();
        asm volatile("s_waitcnt lgkmcnt(0)" ::: "memory");
        __builtin_amdgcn_sched_barrier(0);
        __builtin_amdgcn_s_setprio(1);
#pragma unroll
        for (int ks = 0; ks < 2; ++ks)
#pragma unroll
            for (int mf = 0; mf < 2; ++mf)
#pragma unroll
                for (int nf = 0; nf < 4; ++nf)
                    acc[mf][nf] = __builtin_amdgcn_mfma_f32_16x16x32_bf16(
                        af[mf][ks], bfr[nf][ks], acc[mf][nf], 0, 0, 0);
        __builtin_amdgcn_s_setprio(0);
        __builtin_amdgcn_sched_barrier(0);
        __builtin_amdgcn_s_barrier();

        // ================= phase 2: quadrant mf2-3 x nf0-3 =================
        bf16x8 af2[2][2];
#pragma unroll
        for (int mf = 0; mf < 2; ++mf)
#pragma unroll
            for (int ks = 0; ks < 2; ++ks)
                af2[mf][ks] = *(const bf16x8*)&lAc[(wr*64 + (mf+2)*16 + lr)*BKG + ((ks*32 + lg*8) ^ sw)];
        if (pf) {
            gload_lds16(aS + (size_t)3*64*K + nk0, &lA[pc][(3*64 + wid*8)*BKG]);
            gload_lds16(bS + (size_t)0*64*K + nk0, &lB[pc][(0*64 + wid*8)*BKG]);
            gload_lds16(bS + (size_t)1*64*K + nk0, &lB[pc][(1*64 + wid*8)*BKG]);
            asm volatile("s_waitcnt vmcnt(6)" ::: "memory");  // tile t+1 landed
        } else {
            asm volatile("s_waitcnt vmcnt(0)" ::: "memory");  // drain (last 2 tiles)
        }
        __builtin_amdgcn_s_barrier();
        asm volatile("s_waitcnt lgkmcnt(0)" ::: "memory");
        __builtin_amdgcn_sched_barrier(0);
        __builtin_amdgcn_s_setprio(1);
#pragma unroll
        for (int ks = 0; ks < 2; ++ks)
#pragma unroll
            for (int mf = 0; mf < 2; ++mf)
#pragma unroll
                for (int nf = 0; nf < 4; ++nf)
                    acc[mf+2][nf] = __builtin_amdgcn_mfma_f32_16x16x32_bf16(
                        af2[mf][ks], bfr[nf][ks], acc[mf+2][nf], 0, 0, 0);
        __builtin_amdgcn_s_setprio(0);
        __builtin_amdgcn_sched_barrier(0);
        __builtin_amdgcn_s_barrier();

        cur = (cur + 1 >= 3) ? 0 : cur + 1;
    }

    // ---- epilogue: C row = m0+wr*64+mf*16+lg*4+rr, col = n0+wc*64+nf*16+lr
#pragma unroll
    for (int nf = 0; nf < 4; ++nf) {
        const int col = n0 + wc*64 + nf*16 + lr;
        const float bj = bias[col];
#pragma unroll
        for (int mf = 0; mf < 4; ++mf) {
            const int row0 = m0 + wr*64 + mf*16 + lg*4;
#pragma unroll
            for (int rr = 0; rr < 4; ++rr) {
                float v = acc[mf][nf][rr] + bj;
                const size_t idx = (size_t)(row0 + rr) * N + col;
                if (MODE == 2) {
                    ((float*)Cout)[idx] = v + resid[idx];
                } else {
                    if (MODE == 1) v = 0.5f * v * (1.0f + erff(v * 0.70710678118654752f));
                    ((bf16*)Cout)[idx] = (bf16)v;
                }
            }
        }
    }
}

// ======================================================================
// Flash attention v2 (causal, GQA rep=4). Grid (S/64, NQ, B), 256 thr.
// ======================================================================
__global__ __launch_bounds__(256) void attn_kernel(
    const bf16* __restrict__ qkv, const bf16* __restrict__ Vt,
    bf16* __restrict__ ctx)
{
    __shared__ bf16 lK[2][KVB*HD_];   // [64][128], granule-XOR swizzled
    __shared__ bf16 lV[2][HD_*KVB];   // [128][64], granule-XOR swizzled
    __shared__ bf16 lP[4][16*72];     // per-wave P round-trip
    const int tid  = (int)threadIdx.x;
    const int wid  = tid >> 6;
    const int lane = tid & 63;
    const int lr   = lane & 15;
    const int lg   = lane >> 4;
    const int qt = (int)gridDim.x - 1 - (int)blockIdx.x;  // heavy tiles first
    const int h = (int)blockIdx.y, b = (int)blockIdx.z;
    const int kh = h >> 2;               // REP = 4
    const int qb = qt * 64;
    const int qw = qb + wid * 16;
    const float scale = 0.08838834764831845f;   // 1/sqrt(128)

    const bf16* kB[4];
    const bf16* vB[4];
#pragma unroll
    for (int i = 0; i < 4; ++i) {
        const int kRow = (wid*4 + i)*4 + (lane >> 4);            // 0..63
        const int kCol = ((lane & 15) ^ (kRow & 7)) * 8;          // elems
        kB[i] = qkv + (size_t)(b*S_ + kRow)*QKVN + H_ + kh*HD_ + kCol;
        const int vRow = (wid*4 + i)*8 + (lane >> 3);            // d: 0..127
        const int vCol = ((lane & 7) ^ (vRow & 7)) * 8;           // elems
        vB[i] = Vt + ((size_t)(b*NKV_ + kh)*HD_ + vRow)*S_ + vCol;
    }

    bf16x8 qf[4];
    {
        const bf16* qp = qkv + (size_t)(b*S_ + qw + lr)*QKVN + h*HD_ + lg*8;
#pragma unroll
        for (int t = 0; t < 4; ++t) qf[t] = *(const bf16x8*)(qp + t*32);
    }

    f32x4 o[8] = {};
    float mrow[4] = {-__builtin_inff(), -__builtin_inff(), -__builtin_inff(), -__builtin_inff()};
    float lrow[4] = {0.f, 0.f, 0.f, 0.f};
    const int nt = qt + 1;

#pragma unroll
    for (int i = 0; i < 4; ++i) {
        gload_lds16(kB[i], &lK[0][(wid*4 + i)*4*HD_]);
        gload_lds16(vB[i], &lV[0][(wid*4 + i)*8*KVB]);
    }

    int cur = 0;
    for (int t = 0; t < nt; ++t) {
        __syncthreads();   // drains vmcnt -> buffer `cur` ready; `cur^1` free
        if (t + 1 < nt) {
            const size_t kAdd = (size_t)(t+1)*KVB*QKVN;   // +64 kv rows
            const size_t vAdd = (size_t)(t+1)*KVB;        // +64 kv cols
#pragma unroll
            for (int i = 0; i < 4; ++i) {
                gload_lds16(kB[i] + kAdd, &lK[cur^1][(wid*4 + i)*4*HD_]);
                gload_lds16(vB[i] + vAdd, &lV[cur^1][(wid*4 + i)*8*KVB]);
            }
        }
        const int kv0 = t * KVB;

        f32x4 s[4] = {};
#pragma unroll
        for (int sub = 0; sub < 4; ++sub) {
            const int krow = sub*16 + lr;
            const bf16* kr = &lK[cur][krow*HD_];
            const int swk = (krow & 7) * 8;
#pragma unroll
            for (int d = 0; d < 4; ++d) {
                const bf16x8 kf = *(const bf16x8*)(kr + ((d*32 + lg*8) ^ swk));
                s[sub] = __builtin_amdgcn_mfma_f32_16x16x32_bf16(qf[d], kf, s[sub], 0, 0, 0);
            }
        }

        float p[4][4], rmax[4];
        if (t == qt) {
#pragma unroll
            for (int rr = 0; rr < 4; ++rr) {
                const int q = qw + lg*4 + rr;
                rmax[rr] = -__builtin_inff();
#pragma unroll
                for (int sub = 0; sub < 4; ++sub) {
                    const int kv = kv0 + sub*16 + lr;
                    const float v = s[sub][rr] * scale;
                    p[sub][rr] = (kv <= q) ? v : -__builtin_inff();
                    rmax[rr] = fmaxf(rmax[rr], p[sub][rr]);
                }
            }
        } else {
#pragma unroll
            for (int rr = 0; rr < 4; ++rr) {
                rmax[rr] = -__builtin_inff();
#pragma unroll
                for (int sub = 0; sub < 4; ++sub) {
                    p[sub][rr] = s[sub][rr] * scale;
                    rmax[rr] = fmaxf(rmax[rr], p[sub][rr]);
                }
            }
        }
#pragma unroll
        for (int d = 1; d < 16; d <<= 1)
#pragma unroll
            for (int rr = 0; rr < 4; ++rr)
                rmax[rr] = fmaxf(rmax[rr], __shfl_xor(rmax[rr], d));

        float fsc[4], rsum[4];
#pragma unroll
        for (int rr = 0; rr < 4; ++rr) {
            const float mn = fmaxf(mrow[rr], rmax[rr]);
            fsc[rr]  = __expf(mrow[rr] - mn);
            mrow[rr] = mn;
            rsum[rr] = 0.f;
#pragma unroll
            for (int sub = 0; sub < 4; ++sub) {
                p[sub][rr] = __expf(p[sub][rr] - mn);
                rsum[rr] += p[sub][rr];
            }
        }
#pragma unroll
        for (int d = 1; d < 16; d <<= 1)
#pragma unroll
            for (int rr = 0; rr < 4; ++rr)
                rsum[rr] += __shfl_xor(rsum[rr], d);
#pragma unroll
        for (int rr = 0; rr < 4; ++rr) lrow[rr] = lrow[rr]*fsc[rr] + rsum[rr];
#pragma unroll
        for (int dch = 0; dch < 8; ++dch)
#pragma unroll
            for (int rr = 0; rr < 4; ++rr) o[dch][rr] *= fsc[rr];

#pragma unroll
        for (int sub = 0; sub < 4; ++sub)
#pragma unroll
            for (int rr = 0; rr < 4; ++rr)
                lP[wid][(lg*4 + rr)*72 + sub*16 + lr] = (bf16)p[sub][rr];
        bf16x8 pfr[2];
#pragma unroll
        for (int kk = 0; kk < 2; ++kk)
            pfr[kk] = *(const bf16x8*)&lP[wid][lr*72 + kk*32 + lg*8];

#pragma unroll
        for (int dch = 0; dch < 8; ++dch) {
            const bf16* vr = &lV[cur][(dch*16 + lr)*KVB];
            const int swv = (lr & 7) * 8;
#pragma unroll
            for (int kk = 0; kk < 2; ++kk) {
                const bf16x8 vf = *(const bf16x8*)(vr + ((kk*32 + lg*8) ^ swv));
                o[dch] = __builtin_amdgcn_mfma_f32_16x16x32_bf16(pfr[kk], vf, o[dch], 0, 0, 0);
            }
        }
        cur ^= 1;
    }

#pragma unroll
    for (int rr = 0; rr < 4; ++rr) {
        const float inv = 1.0f / lrow[rr];
        bf16* cp = ctx + (size_t)(b*S_ + qw + lg*4 + rr) * H_ + h*HD_ + lr;
#pragma unroll
        for (int dch = 0; dch < 8; ++dch)
            cp[dch*16] = (bf16)(o[dch][rr] * inv);
    }
}

// ======================================================================
extern "C" void kernel_launch(void* const* d_in, const int* in_sizes, int n_in,
                              void* d_out, int out_size, void* d_ws, size_t ws_size,
                              hipStream_t stream)
{
    const float* hidden = (const float*)d_in[0];
    const float* Wq = (const float*)d_in[1];
    const float* bq = (const float*)d_in[2];
    const float* Wk = (const float*)d_in[3];
    const float* bk = (const float*)d_in[4];
    const float* Wv = (const float*)d_in[5];
    const float* bv = (const float*)d_in[6];
    const float* Wo = (const float*)d_in[7];
    const float* bo = (const float*)d_in[8];
    const float* W1 = (const float*)d_in[9];
    const float* b1 = (const float*)d_in[10];
    const float* W2 = (const float*)d_in[11];
    const float* b2 = (const float*)d_in[12];
    const float* g1 = (const float*)d_in[13];
    const float* g2 = (const float*)d_in[14];
    float* out = (float*)d_out;

    // d_ws is 256 MiB; vt aliases xn1 (dead after QKV GEMM). Total
    // footprint = 264,253,440 B (proven to fit in rounds 1/3).
    char* p = (char*)d_ws;
    auto alloc = [&](size_t bytes) { char* r = p; p += (bytes + 255) & ~(size_t)255; return r; };
    bf16*  wt_qkv = (bf16*)alloc((size_t)QKVN * H_ * 2);   // [3072][2048]
    bf16*  wo_t   = (bf16*)alloc((size_t)H_ * H_ * 2);
    bf16*  w1_t   = (bf16*)alloc((size_t)FF_ * H_ * 2);
    bf16*  w2_t   = (bf16*)alloc((size_t)H_ * FF_ * 2);
    float* bqkv   = (float*)alloc((size_t)QKVN * 4);
    bf16*  xn1    = (bf16*)alloc((size_t)TOK * H_ * 2);    // 16 MB
    bf16*  qkv    = (bf16*)alloc((size_t)TOK * QKVN * 2);
    bf16*  ctxb   = (bf16*)alloc((size_t)TOK * H_ * 2);
    float* x1     = (float*)alloc((size_t)TOK * H_ * 4);
    bf16*  xn2    = (bf16*)alloc((size_t)TOK * H_ * 2);
    bf16*  ffn    = (bf16*)alloc((size_t)TOK * FF_ * 2);
    bf16*  vt     = xn1;   // alias: 4 MB Vt lives in dead xn1 region

    const dim3 blk(256);
    const dim3 blk2(512);
    biaspack_kernel<<<dim3(QKVN/256), blk, 0, stream>>>(bq, bk, bv, bqkv);
    wtrans_kernel<<<dim3(H_/32,  H_/32),  blk, 0, stream>>>(Wq, wt_qkv, H_, H_,  0);
    wtrans_kernel<<<dim3(512/32, H_/32),  blk, 0, stream>>>(Wk, wt_qkv, H_, 512, H_);
    wtrans_kernel<<<dim3(512/32, H_/32),  blk, 0, stream>>>(Wv, wt_qkv, H_, 512, H_ + 512);
    wtrans_kernel<<<dim3(H_/32,  H_/32),  blk, 0, stream>>>(Wo, wo_t,   H_, H_,  0);
    wtrans_kernel<<<dim3(FF_/32, H_/32),  blk, 0, stream>>>(W1, w1_t,   H_, FF_, 0);
    wtrans_kernel<<<dim3(H_/32,  FF_/32), blk, 0, stream>>>(W2, w2_t,   FF_, H_, 0);

    rmsnorm_kernel<<<dim3(TOK), blk, 0, stream>>>(hidden, g1, xn1);
    gemm2_kernel<0><<<dim3(QKVN/BN, TOK/BM), blk2, 0, stream>>>(
        xn1, wt_qkv, bqkv, nullptr, qkv, TOK, QKVN, H_);
    vtrans_kernel<<<dim3(TOK/32, HD_/32, NKV_), blk, 0, stream>>>(qkv, vt);
    attn_kernel<<<dim3(S_/64, NQ_, B_), blk, 0, stream>>>(qkv, vt, ctxb);
    gemm2_kernel<2><<<dim3(H_/BN, TOK/BM), blk2, 0, stream>>>(
        ctxb, wo_t, bo, hidden, x1, TOK, H_, H_);
    rmsnorm_kernel<<<dim3(TOK), blk, 0, stream>>>(x1, g2, xn2);
    gemm2_kernel<1><<<dim3(FF_/BN, TOK/BM), blk2, 0, stream>>>(
        xn2, w1_t, b1, nullptr, ffn, TOK, FF_, H_);
    gemm2_kernel<2><<<dim3(H_/BN, TOK/BM), blk2, 0, stream>>>(
        ffn, w2_t, b2, x1, out, TOK, H_, FF_);
}